// Round 3
// baseline (114916.211 us; speedup 1.0000x reference)
//
#include <hip/hip_runtime.h>

typedef unsigned short u16;
typedef unsigned int   u32;

__device__ __forceinline__ float b2f(u16 h) { return __uint_as_float(((u32)h) << 16); }
__device__ __forceinline__ u16 f2bf(float f) {
  u32 u = __float_as_uint(f);
  return (u16)((u + 0x7fffu + ((u >> 16) & 1u)) >> 16);  // RNE
}
__device__ __forceinline__ float sigmoid_f(float x) { return 1.f / (1.f + __expf(-x)); }

// dtype-adaptive scalar load: element i of tensor p (f32 flag chooses decode)
__device__ __forceinline__ float ldv(const void* p, size_t i, int f32) {
  return f32 ? ((const float*)p)[i] : b2f(((const u16*)p)[i]);
}
// dtype-adaptive 8-element contiguous load (i must be multiple of 8)
__device__ __forceinline__ void ld8(const void* p, size_t i, int f32, float* o) {
  if (f32) {
    const float* q = (const float*)p + i;
    float4 u = *(const float4*)q, v = *(const float4*)(q + 4);
    o[0] = u.x; o[1] = u.y; o[2] = u.z; o[3] = u.w;
    o[4] = v.x; o[5] = v.y; o[6] = v.z; o[7] = v.w;
  } else {
    uint4 u = *(const uint4*)((const u16*)p + i);
    const u32* w = (const u32*)&u;
#pragma unroll
    for (int t = 0; t < 4; t++) {
      o[2 * t]     = b2f((u16)(w[t] & 0xffffu));
      o[2 * t + 1] = b2f((u16)(w[t] >> 16));
    }
  }
}

// ---------------------------------------------------------------------------
// dtype detector: h_0 ~ N(0,1). Real bf16 data: max|first 256 words| < ~6.
// fp32 bit-halves decoded as bf16: low mantissa halves are ~uniform bits ->
// max is ~1e30+ with overwhelming probability. Threshold 1e6 separates.
// ---------------------------------------------------------------------------
__global__ void detect_kernel(const void* __restrict__ h0, int* __restrict__ flag) {
  if (threadIdx.x == 0) {
    const u16* p = (const u16*)h0;
    float mx = 0.f;
    for (int i = 0; i < 256; i++) mx = fmaxf(mx, fabsf(b2f(p[i])));
    flag[0] = (mx > 1.0e6f) ? 1 : 0;
  }
}

// ---------------------------------------------------------------------------
// m_t[m][n] = (emb[inp[m]] . Wmx[n] + bmx[n]) * (h0[m] . Wmh[n] + bmh[n])
// one thread per output; block = 16(n) x 16(m)
// ---------------------------------------------------------------------------
__global__ __launch_bounds__(256) void m_naive(
    const int* __restrict__ inp, const void* __restrict__ h0, const void* __restrict__ emb,
    const void* __restrict__ Wmx, const void* __restrict__ bmx,
    const void* __restrict__ Wmh, const void* __restrict__ bmh,
    u16* __restrict__ M, const int* __restrict__ flag)
{
  const int f32 = *flag;
  const int tid = threadIdx.x;
  const int n = blockIdx.x * 16 + (tid & 15);
  const int m = blockIdx.y * 16 + (tid >> 4);
  const size_t E = 1024, H = 2048;
  float a8[8], w8[8];

  const size_t ar = (size_t)inp[m] * E;
  float ax = 0.f;
  for (size_t k = 0; k < E; k += 8) {
    ld8(emb, ar + k, f32, a8);
    ld8(Wmx, (size_t)n * E + k, f32, w8);
#pragma unroll
    for (int t = 0; t < 8; t++) ax = fmaf(a8[t], w8[t], ax);
  }
  float ah = 0.f;
  for (size_t k = 0; k < H; k += 8) {
    ld8(h0, (size_t)m * H + k, f32, a8);
    ld8(Wmh, (size_t)n * H + k, f32, w8);
#pragma unroll
    for (int t = 0; t < 8; t++) ah = fmaf(a8[t], w8[t], ah);
  }
  float v = (ax + ldv(bmx, n, f32)) * (ah + ldv(bmh, n, f32));
  M[(size_t)m * H + n] = f2bf(v);  // internal m_t always bf16
}

// ---------------------------------------------------------------------------
// four gate pre-activations per (m,n), epilogue writes hx/cx into d_out
// ---------------------------------------------------------------------------
__global__ __launch_bounds__(256) void gates_naive(
    const int* __restrict__ inp, const void* __restrict__ emb, const u16* __restrict__ M,
    const void* __restrict__ Wfx, const void* __restrict__ Wix,
    const void* __restrict__ Wox, const void* __restrict__ Wcx,
    const void* __restrict__ Wfm, const void* __restrict__ Wim,
    const void* __restrict__ Wom, const void* __restrict__ Wcm,
    const void* __restrict__ bfx, const void* __restrict__ bfm,
    const void* __restrict__ bix, const void* __restrict__ bim,
    const void* __restrict__ box_, const void* __restrict__ bom,
    const void* __restrict__ bcx, const void* __restrict__ bcm,
    const void* __restrict__ C0, void* __restrict__ dout, const int* __restrict__ flag)
{
  const int f32 = *flag;
  const int tid = threadIdx.x;
  const int n = blockIdx.x * 16 + (tid & 15);
  const int m = blockIdx.y * 16 + (tid >> 4);
  const size_t E = 1024, H = 2048;
  float aF = 0.f, aI = 0.f, aO = 0.f, aC = 0.f;
  float a8[8], w8[8];

  {  // x-projections (x row = emb[inp[m]], read in place)
    const size_t ar = (size_t)inp[m] * E;
    const size_t wr = (size_t)n * E;
    for (size_t k = 0; k < E; k += 8) {
      ld8(emb, ar + k, f32, a8);
      ld8(Wfx, wr + k, f32, w8);
#pragma unroll
      for (int t = 0; t < 8; t++) aF = fmaf(a8[t], w8[t], aF);
      ld8(Wix, wr + k, f32, w8);
#pragma unroll
      for (int t = 0; t < 8; t++) aI = fmaf(a8[t], w8[t], aI);
      ld8(Wox, wr + k, f32, w8);
#pragma unroll
      for (int t = 0; t < 8; t++) aO = fmaf(a8[t], w8[t], aO);
      ld8(Wcx, wr + k, f32, w8);
#pragma unroll
      for (int t = 0; t < 8; t++) aC = fmaf(a8[t], w8[t], aC);
    }
  }
  {  // m_t-projections (M is internal bf16)
    const size_t mr = (size_t)m * H;
    const size_t wr = (size_t)n * H;
    for (size_t k = 0; k < H; k += 8) {
      ld8(M, mr + k, 0, a8);
      ld8(Wfm, wr + k, f32, w8);
#pragma unroll
      for (int t = 0; t < 8; t++) aF = fmaf(a8[t], w8[t], aF);
      ld8(Wim, wr + k, f32, w8);
#pragma unroll
      for (int t = 0; t < 8; t++) aI = fmaf(a8[t], w8[t], aI);
      ld8(Wom, wr + k, f32, w8);
#pragma unroll
      for (int t = 0; t < 8; t++) aO = fmaf(a8[t], w8[t], aO);
      ld8(Wcm, wr + k, f32, w8);
#pragma unroll
      for (int t = 0; t < 8; t++) aC = fmaf(a8[t], w8[t], aC);
    }
  }
  aF += ldv(bfx, n, f32) + ldv(bfm, n, f32);
  aI += ldv(bix, n, f32) + ldv(bim, n, f32);
  aO += ldv(box_, n, f32) + ldv(bom, n, f32);
  aC += ldv(bcx, n, f32) + ldv(bcm, n, f32);

  float fg = sigmoid_f(aF), ig = sigmoid_f(aI), og = sigmoid_f(aO), ct = tanhf(aC);
  size_t idx = (size_t)m * H + n;
  float c0v = ldv(C0, idx, f32);
  float cx = fg * c0v + ig * ct;
  float hx = og * tanhf(cx);

  size_t eH = (size_t)16384 + idx;                   // hx region (output 1)
  size_t eC = eH + (size_t)8192 * 2048;              // cx region (output 2)
  if (f32) {
    ((float*)dout)[eH] = hx;
    ((float*)dout)[eC] = cx;
  } else {
    ((u16*)dout)[eH] = f2bf(hx);
    ((u16*)dout)[eC] = f2bf(cx);
  }
}

// ---------------------------------------------------------------------------
// out[row][o] = hx[row] . W_dec[o] + b_dec[o]; one thread per output (16384)
// ---------------------------------------------------------------------------
__global__ __launch_bounds__(256) void decoder_naive(
    const void* __restrict__ Wd, const void* __restrict__ bd,
    void* __restrict__ dout, const int* __restrict__ flag)
{
  const int f32 = *flag;
  int gid = blockIdx.x * 256 + threadIdx.x;  // [0, 16384)
  int row = gid >> 1, o = gid & 1;
  float a8[8], w8[8];
  float acc = 0.f;
  const size_t hbase = (size_t)16384 + (size_t)row * 2048;
  const size_t wbase = (size_t)o * 2048;
  for (size_t k = 0; k < 2048; k += 8) {
    ld8(dout, hbase + k, f32, a8);  // read hx back from d_out
    ld8(Wd, wbase + k, f32, w8);
#pragma unroll
    for (int t = 0; t < 8; t++) acc = fmaf(a8[t], w8[t], acc);
  }
  float v = acc + ldv(bd, o, f32);
  size_t oi = (size_t)row * 2 + o;
  if (f32) ((float*)dout)[oi] = v;
  else     ((u16*)dout)[oi] = f2bf(v);
}

extern "C" void kernel_launch(void* const* d_in, const int* in_sizes, int n_in,
                              void* d_out, int out_size, void* d_ws, size_t ws_size,
                              hipStream_t stream)
{
  const int* inp  = (const int*)d_in[0];
  const void* h0  = d_in[1];
  const void* c0  = d_in[2];
  const void* emb = d_in[3];
  const void* Wmx = d_in[4],  *bmx = d_in[5];
  const void* Wmh = d_in[6],  *bmh = d_in[7];
  const void* Wfx = d_in[8],  *bfx = d_in[9];
  const void* Wfm = d_in[10], *bfm = d_in[11];
  const void* Wix = d_in[12], *bix = d_in[13];
  const void* Wim = d_in[14], *bim = d_in[15];
  const void* Wox = d_in[16], *box_ = d_in[17];
  const void* Wom = d_in[18], *bom = d_in[19];
  const void* Wcx = d_in[20], *bcx = d_in[21];
  const void* Wcm = d_in[22], *bcm = d_in[23];
  const void* Wdec = d_in[24], *bdec = d_in[25];

  int* flag = (int*)d_ws;
  u16* Mw = (u16*)((char*)d_ws + 256);  // [8192,2048] bf16 = 32 MB

  detect_kernel<<<1, 64, 0, stream>>>(h0, flag);
  m_naive<<<dim3(128, 512), 256, 0, stream>>>(inp, h0, emb, Wmx, bmx, Wmh, bmh, Mw, flag);
  gates_naive<<<dim3(128, 512), 256, 0, stream>>>(
      inp, emb, Mw, Wfx, Wix, Wox, Wcx, Wfm, Wim, Wom, Wcm,
      bfx, bfm, bix, bim, box_, bom, bcx, bcm, c0, d_out, flag);
  decoder_naive<<<64, 256, 0, stream>>>(Wdec, bdec, d_out, flag);
}